// Round 8
// baseline (233.555 us; speedup 1.0000x reference)
//
#include <hip/hip_runtime.h>
#include <cstdint>
#include <cstddef>

// Problem constants (fixed by the reference)
#define B_      32
#define N_      8400
#define C_      80
#define NC      672000        // N_*C_
#define NCV4    168000        // NC/4
#define NBINS   4096
#define TOPK    1024
#define MAXDET  300
#define CANDCAP 4096
#define NSLICE  16
#define SLICE_V4 10500        // NCV4 / NSLICE
#define NBKT    8             // score bins 4088..4095 (all x in [0.998..1))
#define SEGB    64            // per-(batch,bucket,slice) cap (mean 10.25, 17 sigma)
#define BSORT   256           // per-bucket sort size (mean 164, 7.2 sigma)
#define CTRS    32            // nmsCtr stride in u32 (one 128B line per batch)

// Static stage threshold: score >= 4088/4096 = 0.998046875.
// Expected candidates/batch = 672000*8/4096 = 1312 (sd ~36). Bucket = bin-4088
// partitions candidates into 8 ORDER-DISJOINT groups (floor is monotone, float
// bits are monotone): sorted buckets concatenated 7..0 == exact lax.top_k
// order (score desc, index asc via key low bits). Violating inputs take the
// exact in-kernel histogram fallback (single-wave, never on bench input).
#define STAGE_THRESH 0.998046875f

// Workspace layout (bytes)
#define WS_SEGKEYS  0           // 32*8*16*64*8 = 2097152
#define WS_SEGCNT   2097152     // 32*8*16*4    = 16384
#define WS_NMSCTR   2113536     // 32*32*4      = 4096
#define WS_TOPSCORE 2117632     // 32*1024*4    = 131072
#define WS_TOPBOX   2248704     // 32*1024*16   = 524288
#define WS_TOPCLS   2772992     // 32*1024*4    = 131072
#define WS_KEEP     2904064     // 32*1024*4    = 131072

// Output layout (float32, concatenated): boxes[32][300][4], scores[32][300],
// labels[32][300], n_valid[32]
#define OUT_SCORES  38400
#define OUT_LABELS  48000
#define OUT_NVALID  57600

// ---------------------------------------------------------------------------
// K1: single-pass filter+stage into PRIVATE per-(batch,bucket,slice) segments.
// key = (bits(v)<<32) | ~flat_idx. 8 LDS counters per block; plain global
// stores; no global atomics, no pre-zeroing (raw counts let sortb detect
// overflow -> fallback). Slice-0 blocks also zero the batch's nms counter.
__global__ __launch_bounds__(256) void stage_kernel(const float4* __restrict__ scores4,
                                                    unsigned* __restrict__ segCnt,
                                                    unsigned long long* __restrict__ segKeys,
                                                    unsigned* __restrict__ nmsCtr) {
    __shared__ unsigned lcnt[NBKT];
    int b = blockIdx.x, sl = blockIdx.y, tid = threadIdx.x;
    if (tid < NBKT) lcnt[tid] = 0;
    if (sl == 0 && tid == 0) nmsCtr[b * CTRS] = 0;
    __syncthreads();
    const float4* s = scores4 + (size_t)b * NCV4 + (size_t)sl * SLICE_V4;
    for (int i = tid; i < SLICE_V4; i += 256) {
        float4 v = s[i];
        float c[4] = {v.x, v.y, v.z, v.w};
        unsigned flat0 = ((unsigned)sl * SLICE_V4 + (unsigned)i) * 4u;
        #pragma unroll
        for (int kc = 0; kc < 4; ++kc) {
            float x = (c[kc] > 0.001f) ? c[kc] : 0.0f;
            if (x >= STAGE_THRESH) {
                int bin = (int)(x * 4096.0f);             // exact: x * 2^12
                bin = bin > (NBINS - 1) ? (NBINS - 1) : bin;
                int bkt = bin - 4088;                      // 0..7
                unsigned p = atomicAdd(&lcnt[bkt], 1u);
                if (p < (unsigned)SEGB)
                    segKeys[(((size_t)(b * NBKT + bkt)) * NSLICE + sl) * SEGB + p] =
                        ((unsigned long long)__float_as_uint(x) << 32) |
                        (unsigned long long)(0xFFFFFFFFu - (flat0 + kc));
            }
        }
    }
    __syncthreads();
    if (tid < NBKT) segCnt[(b * NBKT + tid) * NSLICE + sl] = lcnt[tid];
}

// ---------------------------------------------------------------------------
// K2: one WAVE per (batch,bucket) — 256 parallel blocks. Fast path: load the
// bucket (<=256 keys), barrier-free single-wave bitonic sort, write
// topScore/topBox/topCls at [base, base+n) for ranks < 1024. Invalid inputs
// (cap overflow or M outside [TOPK,CANDCAP]): block (b,0) runs the exact
// histogram fallback single-wave (speed irrelevant — never taken on bench).
__global__ __launch_bounds__(64) void sortb_kernel(
        const float4* __restrict__ scores4,
        const unsigned long long* __restrict__ segKeys,
        const unsigned* __restrict__ segCnt,
        const float4* __restrict__ boxes4,
        float* __restrict__ topScore,
        float4* __restrict__ topBox4,
        int* __restrict__ topCls) {
    __shared__ unsigned long long kbuf[CANDCAP];    // 32 KB (fast path uses 256)
    __shared__ unsigned bsum[NBKT];
    __shared__ unsigned bok[NBKT];
    __shared__ unsigned spref[NSLICE + 1];
    __shared__ unsigned scnt;
    __shared__ int s_cut;
    int b = blockIdx.x, bkt = blockIdx.y, lane = threadIdx.x;

    // per-bucket totals + per-segment cap check (whole batch, all lanes agree)
    if (lane < NBKT) {
        const unsigned* c = segCnt + (b * NBKT + lane) * NSLICE;
        unsigned ssum = 0, ok = 1;
        for (int sl = 0; sl < NSLICE; ++sl) {
            unsigned v = c[sl];
            if (v > (unsigned)SEGB) ok = 0;
            ssum += v;
        }
        bsum[lane] = ssum; bok[lane] = ok;
    }
    __threadfence_block();
    unsigned M = 0, base = 0; int valid = 1;
    #pragma unroll
    for (int t = 0; t < NBKT; ++t) {
        unsigned s2 = bsum[t];
        if (!bok[t] || s2 > (unsigned)BSORT) valid = 0;
        M += s2;
        if (t > bkt) base += s2;
    }
    unsigned n = bsum[bkt];
    if (M < (unsigned)TOPK || M > (unsigned)CANDCAP) valid = 0;

    if (valid) {
        if (base >= (unsigned)TOPK || n == 0) return;
        // concatenate this bucket's 16 slice-segments into LDS
        if (lane == 0) {
            unsigned acc = 0; spref[0] = 0;
            const unsigned* c = segCnt + (b * NBKT + bkt) * NSLICE;
            for (int sl = 0; sl < NSLICE; ++sl) { acc += c[sl]; spref[sl + 1] = acc; }
        }
        __threadfence_block();
        for (int sl = 0; sl < NSLICE; ++sl) {
            unsigned b0 = spref[sl], c2 = spref[sl + 1] - b0;
            const unsigned long long* src =
                segKeys + (((size_t)(b * NBKT + bkt)) * NSLICE + sl) * SEGB;
            for (unsigned t = lane; t < c2; t += 64) kbuf[b0 + t] = src[t];
        }
        for (unsigned t = n + lane; t < (unsigned)BSORT; t += 64) kbuf[t] = 0ull;
        __threadfence_block();
        // single-wave bitonic sort, descending — lockstep, no barriers
        for (int kk = 2; kk <= BSORT; kk <<= 1) {
            for (int j = kk >> 1; j > 0; j >>= 1) {
                for (int c2 = lane; c2 < BSORT / 2; c2 += 64) {
                    int t = ((c2 & ~(j - 1)) << 1) | (c2 & (j - 1));
                    int l = t | j;
                    unsigned long long a0 = kbuf[t], c0 = kbuf[l];
                    bool sw = ((t & kk) == 0) ? (a0 < c0) : (a0 > c0);
                    if (sw) { kbuf[t] = c0; kbuf[l] = a0; }
                }
                __threadfence_block();
            }
        }
        unsigned wlim = (unsigned)TOPK - base; if (wlim > n) wlim = n;
        for (unsigned r = lane; r < wlim; r += 64) {
            unsigned long long key = kbuf[r];
            float sc = __uint_as_float((unsigned)(key >> 32));
            unsigned idx = 0xFFFFFFFFu - (unsigned)(key & 0xFFFFFFFFull);
            if (idx >= (unsigned)NC) idx = 0;    // defensive
            unsigned bi = idx / (unsigned)C_;
            unsigned cl = idx - bi * (unsigned)C_;
            unsigned pos = base + r;
            topScore[b * TOPK + pos] = sc;
            topBox4[b * TOPK + pos] = boxes4[(size_t)b * N_ + bi];
            topCls[b * TOPK + pos] = (int)cl;
        }
        return;
    }

    // ---- exact fallback: only block (b, bkt=0); single wave, fences only.
    if (bkt != 0) return;
    unsigned* fh = (unsigned*)kbuf;      // aliases kbuf; dead before kbuf written
    for (int i2 = lane; i2 < NBINS; i2 += 64) fh[i2] = 0;
    if (lane == 0) scnt = 0;
    __threadfence_block();
    const float4* s = scores4 + (size_t)b * NCV4;
    for (int i2 = lane; i2 < NCV4; i2 += 64) {
        float4 v = s[i2];
        float c4[4] = {v.x, v.y, v.z, v.w};
        #pragma unroll
        for (int kc = 0; kc < 4; ++kc) {
            float x = (c4[kc] > 0.001f) ? c4[kc] : 0.0f;
            int bin = (int)(x * 4096.0f);
            bin = bin > (NBINS - 1) ? (NBINS - 1) : bin;
            atomicAdd(&fh[bin], 1u);
        }
    }
    __threadfence_block();
    if (lane == 0) {
        unsigned acc = 0; int cb = 0;
        for (int bin = NBINS - 1; bin >= 0; --bin) {
            acc += fh[bin];
            if (acc >= (unsigned)TOPK) { cb = bin; break; }
        }
        s_cut = cb;
    }
    __threadfence_block();               // lane0's fh reads done (lockstep)
    int cb = s_cut;
    for (int i2 = lane; i2 < NCV4; i2 += 64) {
        float4 v = s[i2];
        float c4[4] = {v.x, v.y, v.z, v.w};
        unsigned flat0 = (unsigned)i2 * 4u;
        #pragma unroll
        for (int kc = 0; kc < 4; ++kc) {
            float x = (c4[kc] > 0.001f) ? c4[kc] : 0.0f;
            int bin = (int)(x * 4096.0f);
            bin = bin > (NBINS - 1) ? (NBINS - 1) : bin;
            if (bin >= cb) {
                unsigned p = atomicAdd(&scnt, 1u);
                if (p < (unsigned)CANDCAP)
                    kbuf[p] = ((unsigned long long)__float_as_uint(x) << 32) |
                              (unsigned long long)(0xFFFFFFFFu - (flat0 + kc));
            }
        }
    }
    __threadfence_block();
    unsigned M2 = scnt; if (M2 > (unsigned)CANDCAP) M2 = CANDCAP;
    int S = (M2 <= 1024u) ? 1024 : (M2 <= 2048u ? 2048 : CANDCAP);
    for (int i2 = (int)M2 + lane; i2 < S; i2 += 64) kbuf[i2] = 0ull;
    __threadfence_block();
    for (int kk = 2; kk <= S; kk <<= 1) {
        for (int j = kk >> 1; j > 0; j >>= 1) {
            for (int t = lane; t < S; t += 64) {
                int l = t ^ j;
                if (l > t) {
                    unsigned long long a0 = kbuf[t], c0 = kbuf[l];
                    bool sw = ((t & kk) == 0) ? (a0 < c0) : (a0 > c0);
                    if (sw) { kbuf[t] = c0; kbuf[l] = a0; }
                }
            }
            __threadfence_block();
        }
    }
    for (int r = lane; r < TOPK; r += 64) {
        unsigned long long key = kbuf[r];
        float sc = __uint_as_float((unsigned)(key >> 32));
        unsigned idx = 0xFFFFFFFFu - (unsigned)(key & 0xFFFFFFFFull);
        if (idx >= (unsigned)NC) idx = 0;
        unsigned bi = idx / (unsigned)C_;
        unsigned cl = idx - bi * (unsigned)C_;
        topScore[b * TOPK + r] = sc;
        topBox4[b * TOPK + r] = boxes4[(size_t)b * N_ + bi];
        topCls[b * TOPK + r] = (int)cl;
    }
}

// ---------------------------------------------------------------------------
// K3: per-(batch,class) greedy NMS + last-block-done finalize.
// Cross-class IoU is exactly 0 (offset gap 4096 >> max box 640), so per-class
// greedy NMS == reference's global sequential loop. IoU replicated in f32 with
// __fmul_rn to block FMA contraction. After writing keep, each block does
// release-fence + device atomic; the 80th block per batch acquires and runs
// the stable top-300 finalize with its 64 lanes.
#define CLS_CAP 256
__global__ __launch_bounds__(64) void nms_fin_kernel(const float* __restrict__ topScore,
                                                     const float* __restrict__ topBox,
                                                     const int* __restrict__ topCls,
                                                     int* __restrict__ keep,
                                                     unsigned* __restrict__ nmsCtr,
                                                     float* __restrict__ out) {
    __shared__ unsigned short pos[CLS_CAP];
    __shared__ float by1[CLS_CAP], bx1[CLS_CAP], by2[CLS_CAP], bx2[CLS_CAP];
    __shared__ float barea[CLS_CAP];
    __shared__ unsigned char sup[CLS_CAP];
    __shared__ int sel[MAXDET];
    __shared__ unsigned s_done;
    int b = blockIdx.x;
    int c = blockIdx.y;
    int lane = threadIdx.x;
    const float* ts = topScore + b * TOPK;
    const int*   tc = topCls + b * TOPK;
    int*         kp = keep + b * TOPK;
    float off = (float)c * 4096.0f;         // exact
    int base = 0;
    for (int chunkS = 0; chunkS < TOPK; chunkS += 64) {
        int i = chunkS + lane;
        int cls = tc[i];
        float sc = ts[i];
        bool mine = (cls == c);
        bool listed = mine && (sc > 0.001f);
        if (mine) kp[i] = 0;                 // default; kept ones overwritten below
        unsigned long long mask = __ballot(listed);
        int rank = __popcll(mask & ((1ull << lane) - 1ull));
        if (listed) {
            int slot = base + rank;
            if (slot < CLS_CAP) {
                pos[slot] = (unsigned short)i;
                const float* tb = topBox + ((size_t)(b * TOPK + i)) * 4;
                float y1 = tb[0] + off, x1 = tb[1] + off;
                float y2 = tb[2] + off, x2 = tb[3] + off;
                by1[slot] = y1; bx1[slot] = x1; by2[slot] = y2; bx2[slot] = x2;
                barea[slot] = __fmul_rn((x2 - x1) + 1.0f, (y2 - y1) + 1.0f);
                sup[slot] = 0;
            }
        }
        base += __popcll(mask);
    }
    int m = base < CLS_CAP ? base : CLS_CAP;
    __syncthreads();
    int cur = 0;
    while (cur < m) {
        // invariant: slot `cur` is unsuppressed -> kept
        if (lane == 0) kp[pos[cur]] = 1;
        float cy1 = by1[cur], cx1 = bx1[cur], cy2 = by2[cur], cx2 = bx2[cur];
        float carea = barea[cur];
        for (int j = cur + 1 + lane; j < m; j += 64) {
            if (!sup[j]) {
                float yy1 = fmaxf(cy1, by1[j]), xx1 = fmaxf(cx1, bx1[j]);
                float yy2 = fminf(cy2, by2[j]), xx2 = fminf(cx2, bx2[j]);
                float w = fmaxf(0.0f, (xx2 - xx1) + 1.0f);
                float h = fmaxf(0.0f, (yy2 - yy1) + 1.0f);
                float inter = __fmul_rn(w, h);
                float denom = (carea + barea[j]) - inter;
                float iou = inter / denom;
                if (iou > 0.7f) sup[j] = 1;
            }
        }
        __syncthreads();
        int nxt = m;
        for (int j = cur + 1 + lane; j < m; j += 64)
            if (!sup[j]) { nxt = j; break; }
        for (int o = 32; o > 0; o >>= 1) {
            int other = __shfl_xor(nxt, o, 64);
            nxt = nxt < other ? nxt : other;
        }
        cur = nxt;
    }

    // --- last-block-done finalize
    __threadfence();                         // release this block's keep writes
    if (lane == 0) s_done = atomicAdd(&nmsCtr[b * CTRS], 1u);
    __syncthreads();
    if (s_done != (unsigned)(C_ - 1)) return;
    __threadfence();                         // acquire all 80 blocks' keep writes

    // stable top-300: kept positions in order, then suppressed in order.
    // lane owns contiguous chunk [lane*16, lane*16+16).
    int lb = lane * 16;
    int kv[16];
    int loc[16];                             // exclusive prefix within chunk
    int csum = 0;
    #pragma unroll
    for (int t = 0; t < 16; ++t) {
        kv[t] = kp[lb + t];
        loc[t] = csum;
        csum += kv[t];
    }
    int incl = csum;                         // wave inclusive scan of chunk sums
    for (int o = 1; o < 64; o <<= 1) {
        int y = __shfl_up(incl, o, 64);
        if (lane >= o) incl += y;
    }
    int nk = __shfl(incl, 63, 64);
    int cexcl = incl - csum;
    #pragma unroll
    for (int t = 0; t < 16; ++t) {
        int i = lb + t;
        int kexcl = cexcl + loc[t];
        if (kv[t]) {
            if (kexcl < MAXDET) sel[kexcl] = i;
        } else {
            int slot = nk + (i - kexcl);
            if (slot < MAXDET) sel[slot] = i;
        }
    }
    __threadfence_block();
    for (int r = lane; r < MAXDET; r += 64) {
        int p = sel[r];
        float sc = (r < nk) ? ts[p] : 0.0f;
        ((float4*)out)[b * MAXDET + r] = ((const float4*)topBox)[b * TOPK + p];
        out[OUT_SCORES + b * MAXDET + r] = sc;
        out[OUT_LABELS + b * MAXDET + r] = (float)tc[p];
    }
    if (lane == 0) out[OUT_NVALID + b] = (float)(nk < MAXDET ? nk : MAXDET);
}

// ---------------------------------------------------------------------------
extern "C" void kernel_launch(void* const* d_in, const int* in_sizes, int n_in,
                              void* d_out, int out_size, void* d_ws, size_t ws_size,
                              hipStream_t stream) {
    const float* boxes  = (const float*)d_in[0];   // (32, 8400, 4)
    const float* scores = (const float*)d_in[1];   // (32, 8400, 80)
    float* out = (float*)d_out;
    char* ws = (char*)d_ws;

    unsigned long long* segKeys = (unsigned long long*)(ws + WS_SEGKEYS);
    unsigned* segCnt = (unsigned*)(ws + WS_SEGCNT);
    unsigned* nmsCtr = (unsigned*)(ws + WS_NMSCTR);
    float* topScore = (float*)(ws + WS_TOPSCORE);
    float* topBox = (float*)(ws + WS_TOPBOX);
    int* topCls = (int*)(ws + WS_TOPCLS);
    int* keep = (int*)(ws + WS_KEEP);

    const float4* scores4 = (const float4*)scores;
    const float4* boxes4  = (const float4*)boxes;

    stage_kernel<<<dim3(B_, NSLICE), 256, 0, stream>>>(scores4, segCnt, segKeys, nmsCtr);
    sortb_kernel<<<dim3(B_, NBKT), 64, 0, stream>>>(scores4, segKeys, segCnt, boxes4,
                                                    topScore, (float4*)topBox, topCls);
    nms_fin_kernel<<<dim3(B_, C_), 64, 0, stream>>>(topScore, topBox, topCls, keep,
                                                    nmsCtr, out);
}

// Round 9
// 189.613 us; speedup vs baseline: 1.2317x; 1.2317x over previous
//
#include <hip/hip_runtime.h>
#include <cstdint>
#include <cstddef>

// Problem constants (fixed by the reference)
#define B_      32
#define N_      8400
#define C_      80
#define NC      672000        // N_*C_
#define NCV4    168000        // NC/4
#define NBINS   4096
#define TOPK    1024
#define MAXDET  300
#define CANDCAP 4096
#define NSLICE  16
#define SLICE_V4 10500        // NCV4 / NSLICE
#define NBKT    8             // score bins 4088..4095 (all x in [0.998..1))
#define SEGB    64            // per-(batch,bucket,slice) cap (mean 10.25, 17 sigma)
#define BSORT   256           // per-bucket sort size (mean 164, 7.2 sigma)

// Static stage threshold: score >= 4088/4096 = 0.998046875.
// Expected candidates/batch = 672000*8/4096 = 1312 (sd ~36). Bucket = bin-4088
// partitions candidates into 8 ORDER-DISJOINT groups (floor is monotone, float
// bits are monotone): sorted buckets concatenated 7..0 == exact lax.top_k
// order (score desc, index asc via key low bits). Violating inputs take the
// exact in-kernel histogram fallback (single-wave, never on bench input).
#define STAGE_THRESH 0.998046875f

// Workspace layout (bytes)
#define WS_SEGKEYS  0           // 32*8*16*64*8 = 2097152
#define WS_SEGCNT   2097152     // 32*8*16*4    = 16384
#define WS_TOPSCORE 2113536     // 32*1024*4    = 131072
#define WS_TOPBOX   2244608     // 32*1024*16   = 524288
#define WS_TOPCLS   2768896     // 32*1024*4    = 131072
#define WS_KEEP     2899968     // 32*1024*4    = 131072

// Output layout (float32, concatenated): boxes[32][300][4], scores[32][300],
// labels[32][300], n_valid[32]
#define OUT_SCORES  38400
#define OUT_LABELS  48000
#define OUT_NVALID  57600

// ---------------------------------------------------------------------------
// K1: single-pass filter+stage into PRIVATE per-(batch,bucket,slice) segments.
// key = (bits(v)<<32) | ~flat_idx. 8 LDS counters per block; plain global
// stores; no global atomics, no pre-zeroing (raw counts let sortb detect
// overflow -> fallback).
__global__ __launch_bounds__(256) void stage_kernel(const float4* __restrict__ scores4,
                                                    unsigned* __restrict__ segCnt,
                                                    unsigned long long* __restrict__ segKeys) {
    __shared__ unsigned lcnt[NBKT];
    int b = blockIdx.x, sl = blockIdx.y, tid = threadIdx.x;
    if (tid < NBKT) lcnt[tid] = 0;
    __syncthreads();
    const float4* s = scores4 + (size_t)b * NCV4 + (size_t)sl * SLICE_V4;
    for (int i = tid; i < SLICE_V4; i += 256) {
        float4 v = s[i];
        float c[4] = {v.x, v.y, v.z, v.w};
        unsigned flat0 = ((unsigned)sl * SLICE_V4 + (unsigned)i) * 4u;
        #pragma unroll
        for (int kc = 0; kc < 4; ++kc) {
            float x = (c[kc] > 0.001f) ? c[kc] : 0.0f;
            if (x >= STAGE_THRESH) {
                int bin = (int)(x * 4096.0f);             // exact: x * 2^12
                bin = bin > (NBINS - 1) ? (NBINS - 1) : bin;
                int bkt = bin - 4088;                      // 0..7
                unsigned p = atomicAdd(&lcnt[bkt], 1u);
                if (p < (unsigned)SEGB)
                    segKeys[(((size_t)(b * NBKT + bkt)) * NSLICE + sl) * SEGB + p] =
                        ((unsigned long long)__float_as_uint(x) << 32) |
                        (unsigned long long)(0xFFFFFFFFu - (flat0 + kc));
            }
        }
    }
    __syncthreads();
    if (tid < NBKT) segCnt[(b * NBKT + tid) * NSLICE + sl] = lcnt[tid];
}

// ---------------------------------------------------------------------------
// K2: one WAVE per (batch,bucket) — 256 parallel blocks. Fast path: load the
// bucket (<=256 keys), barrier-free single-wave bitonic sort, write
// topScore/topBox/topCls at [base, base+n) for ranks < 1024. Invalid inputs
// (cap overflow or M outside [TOPK,CANDCAP]): block (b,0) runs the exact
// histogram fallback single-wave (speed irrelevant — never taken on bench).
// NO device fences, no cross-block signaling (R8 lesson: 2560 __threadfence()
// cost ~70 us on 8 non-coherent XCDs — far more than the launch they saved).
__global__ __launch_bounds__(64) void sortb_kernel(
        const float4* __restrict__ scores4,
        const unsigned long long* __restrict__ segKeys,
        const unsigned* __restrict__ segCnt,
        const float4* __restrict__ boxes4,
        float* __restrict__ topScore,
        float4* __restrict__ topBox4,
        int* __restrict__ topCls) {
    __shared__ unsigned long long kbuf[CANDCAP];    // 32 KB (fast path uses 256)
    __shared__ unsigned bsum[NBKT];
    __shared__ unsigned bok[NBKT];
    __shared__ unsigned spref[NSLICE + 1];
    __shared__ unsigned scnt;
    __shared__ int s_cut;
    int b = blockIdx.x, bkt = blockIdx.y, lane = threadIdx.x;

    // per-bucket totals + per-segment cap check (whole batch, all lanes agree)
    if (lane < NBKT) {
        const unsigned* c = segCnt + (b * NBKT + lane) * NSLICE;
        unsigned ssum = 0, ok = 1;
        for (int sl = 0; sl < NSLICE; ++sl) {
            unsigned v = c[sl];
            if (v > (unsigned)SEGB) ok = 0;
            ssum += v;
        }
        bsum[lane] = ssum; bok[lane] = ok;
    }
    __threadfence_block();
    unsigned M = 0, base = 0; int valid = 1;
    #pragma unroll
    for (int t = 0; t < NBKT; ++t) {
        unsigned s2 = bsum[t];
        if (!bok[t] || s2 > (unsigned)BSORT) valid = 0;
        M += s2;
        if (t > bkt) base += s2;
    }
    unsigned n = bsum[bkt];
    if (M < (unsigned)TOPK || M > (unsigned)CANDCAP) valid = 0;

    if (valid) {
        if (base >= (unsigned)TOPK || n == 0) return;
        // concatenate this bucket's 16 slice-segments into LDS
        if (lane == 0) {
            unsigned acc = 0; spref[0] = 0;
            const unsigned* c = segCnt + (b * NBKT + bkt) * NSLICE;
            for (int sl = 0; sl < NSLICE; ++sl) { acc += c[sl]; spref[sl + 1] = acc; }
        }
        __threadfence_block();
        for (int sl = 0; sl < NSLICE; ++sl) {
            unsigned b0 = spref[sl], c2 = spref[sl + 1] - b0;
            const unsigned long long* src =
                segKeys + (((size_t)(b * NBKT + bkt)) * NSLICE + sl) * SEGB;
            for (unsigned t = lane; t < c2; t += 64) kbuf[b0 + t] = src[t];
        }
        for (unsigned t = n + lane; t < (unsigned)BSORT; t += 64) kbuf[t] = 0ull;
        __threadfence_block();
        // single-wave bitonic sort, descending — lockstep, no barriers
        for (int kk = 2; kk <= BSORT; kk <<= 1) {
            for (int j = kk >> 1; j > 0; j >>= 1) {
                for (int c2 = lane; c2 < BSORT / 2; c2 += 64) {
                    int t = ((c2 & ~(j - 1)) << 1) | (c2 & (j - 1));
                    int l = t | j;
                    unsigned long long a0 = kbuf[t], c0 = kbuf[l];
                    bool sw = ((t & kk) == 0) ? (a0 < c0) : (a0 > c0);
                    if (sw) { kbuf[t] = c0; kbuf[l] = a0; }
                }
                __threadfence_block();
            }
        }
        unsigned wlim = (unsigned)TOPK - base; if (wlim > n) wlim = n;
        for (unsigned r = lane; r < wlim; r += 64) {
            unsigned long long key = kbuf[r];
            float sc = __uint_as_float((unsigned)(key >> 32));
            unsigned idx = 0xFFFFFFFFu - (unsigned)(key & 0xFFFFFFFFull);
            if (idx >= (unsigned)NC) idx = 0;    // defensive
            unsigned bi = idx / (unsigned)C_;
            unsigned cl = idx - bi * (unsigned)C_;
            unsigned pos = base + r;
            topScore[b * TOPK + pos] = sc;
            topBox4[b * TOPK + pos] = boxes4[(size_t)b * N_ + bi];
            topCls[b * TOPK + pos] = (int)cl;
        }
        return;
    }

    // ---- exact fallback: only block (b, bkt=0); single wave, fences only.
    if (bkt != 0) return;
    unsigned* fh = (unsigned*)kbuf;      // aliases kbuf; dead before kbuf written
    for (int i2 = lane; i2 < NBINS; i2 += 64) fh[i2] = 0;
    if (lane == 0) scnt = 0;
    __threadfence_block();
    const float4* s = scores4 + (size_t)b * NCV4;
    for (int i2 = lane; i2 < NCV4; i2 += 64) {
        float4 v = s[i2];
        float c4[4] = {v.x, v.y, v.z, v.w};
        #pragma unroll
        for (int kc = 0; kc < 4; ++kc) {
            float x = (c4[kc] > 0.001f) ? c4[kc] : 0.0f;
            int bin = (int)(x * 4096.0f);
            bin = bin > (NBINS - 1) ? (NBINS - 1) : bin;
            atomicAdd(&fh[bin], 1u);
        }
    }
    __threadfence_block();
    if (lane == 0) {
        unsigned acc = 0; int cb = 0;
        for (int bin = NBINS - 1; bin >= 0; --bin) {
            acc += fh[bin];
            if (acc >= (unsigned)TOPK) { cb = bin; break; }
        }
        s_cut = cb;
    }
    __threadfence_block();               // lane0's fh reads done (lockstep)
    int cb = s_cut;
    for (int i2 = lane; i2 < NCV4; i2 += 64) {
        float4 v = s[i2];
        float c4[4] = {v.x, v.y, v.z, v.w};
        unsigned flat0 = (unsigned)i2 * 4u;
        #pragma unroll
        for (int kc = 0; kc < 4; ++kc) {
            float x = (c4[kc] > 0.001f) ? c4[kc] : 0.0f;
            int bin = (int)(x * 4096.0f);
            bin = bin > (NBINS - 1) ? (NBINS - 1) : bin;
            if (bin >= cb) {
                unsigned p = atomicAdd(&scnt, 1u);
                if (p < (unsigned)CANDCAP)
                    kbuf[p] = ((unsigned long long)__float_as_uint(x) << 32) |
                              (unsigned long long)(0xFFFFFFFFu - (flat0 + kc));
            }
        }
    }
    __threadfence_block();
    unsigned M2 = scnt; if (M2 > (unsigned)CANDCAP) M2 = CANDCAP;
    int S = (M2 <= 1024u) ? 1024 : (M2 <= 2048u ? 2048 : CANDCAP);
    for (int i2 = (int)M2 + lane; i2 < S; i2 += 64) kbuf[i2] = 0ull;
    __threadfence_block();
    for (int kk = 2; kk <= S; kk <<= 1) {
        for (int j = kk >> 1; j > 0; j >>= 1) {
            for (int t = lane; t < S; t += 64) {
                int l = t ^ j;
                if (l > t) {
                    unsigned long long a0 = kbuf[t], c0 = kbuf[l];
                    bool sw = ((t & kk) == 0) ? (a0 < c0) : (a0 > c0);
                    if (sw) { kbuf[t] = c0; kbuf[l] = a0; }
                }
            }
            __threadfence_block();
        }
    }
    for (int r = lane; r < TOPK; r += 64) {
        unsigned long long key = kbuf[r];
        float sc = __uint_as_float((unsigned)(key >> 32));
        unsigned idx = 0xFFFFFFFFu - (unsigned)(key & 0xFFFFFFFFull);
        if (idx >= (unsigned)NC) idx = 0;
        unsigned bi = idx / (unsigned)C_;
        unsigned cl = idx - bi * (unsigned)C_;
        topScore[b * TOPK + r] = sc;
        topBox4[b * TOPK + r] = boxes4[(size_t)b * N_ + bi];
        topCls[b * TOPK + r] = (int)cl;
    }
}

// ---------------------------------------------------------------------------
// K3: per-(batch,class) greedy NMS, one 64-thread block per (b,c).
// Cross-class IoU is exactly 0 (offset gap 4096 >> max box 640), so per-class
// greedy NMS is exactly equivalent to the reference's global sequential loop.
// IoU replicated in f32 with __fmul_rn to block FMA contraction.
#define CLS_CAP 256
__global__ __launch_bounds__(64) void nms_kernel(const float* __restrict__ topScore,
                                                 const float* __restrict__ topBox,
                                                 const int* __restrict__ topCls,
                                                 int* __restrict__ keep) {
    __shared__ unsigned short pos[CLS_CAP];
    __shared__ float by1[CLS_CAP], bx1[CLS_CAP], by2[CLS_CAP], bx2[CLS_CAP];
    __shared__ float barea[CLS_CAP];
    __shared__ unsigned char sup[CLS_CAP];
    int b = blockIdx.x;
    int c = blockIdx.y;
    int lane = threadIdx.x;
    const float* ts = topScore + b * TOPK;
    const int*   tc = topCls + b * TOPK;
    int*         kp = keep + b * TOPK;
    float off = (float)c * 4096.0f;         // exact
    int base = 0;
    for (int chunkS = 0; chunkS < TOPK; chunkS += 64) {
        int i = chunkS + lane;
        int cls = tc[i];
        float sc = ts[i];
        bool mine = (cls == c);
        bool listed = mine && (sc > 0.001f);
        if (mine) kp[i] = 0;                 // default; kept ones overwritten below
        unsigned long long mask = __ballot(listed);
        int rank = __popcll(mask & ((1ull << lane) - 1ull));
        if (listed) {
            int slot = base + rank;
            if (slot < CLS_CAP) {
                pos[slot] = (unsigned short)i;
                const float* tb = topBox + ((size_t)(b * TOPK + i)) * 4;
                float y1 = tb[0] + off, x1 = tb[1] + off;
                float y2 = tb[2] + off, x2 = tb[3] + off;
                by1[slot] = y1; bx1[slot] = x1; by2[slot] = y2; bx2[slot] = x2;
                barea[slot] = __fmul_rn((x2 - x1) + 1.0f, (y2 - y1) + 1.0f);
                sup[slot] = 0;
            }
        }
        base += __popcll(mask);
    }
    int m = base < CLS_CAP ? base : CLS_CAP;
    __syncthreads();
    int cur = 0;
    while (cur < m) {
        // invariant: slot `cur` is unsuppressed -> kept
        if (lane == 0) kp[pos[cur]] = 1;
        float cy1 = by1[cur], cx1 = bx1[cur], cy2 = by2[cur], cx2 = bx2[cur];
        float carea = barea[cur];
        for (int j = cur + 1 + lane; j < m; j += 64) {
            if (!sup[j]) {
                float yy1 = fmaxf(cy1, by1[j]), xx1 = fmaxf(cx1, bx1[j]);
                float yy2 = fminf(cy2, by2[j]), xx2 = fminf(cx2, bx2[j]);
                float w = fmaxf(0.0f, (xx2 - xx1) + 1.0f);
                float h = fmaxf(0.0f, (yy2 - yy1) + 1.0f);
                float inter = __fmul_rn(w, h);
                float denom = (carea + barea[j]) - inter;
                float iou = inter / denom;
                if (iou > 0.7f) sup[j] = 1;
            }
        }
        __syncthreads();
        int nxt = m;
        for (int j = cur + 1 + lane; j < m; j += 64)
            if (!sup[j]) { nxt = j; break; }
        for (int o = 32; o > 0; o >>= 1) {
            int other = __shfl_xor(nxt, o, 64);
            nxt = nxt < other ? nxt : other;
        }
        cur = nxt;
    }
}

// ---------------------------------------------------------------------------
// K4: stable top-300 of final_scores: kept positions in order, then suppressed
// positions in order (score-0 ties break by lower index). Write all outputs.
__global__ __launch_bounds__(1024) void finalize_kernel(const float* __restrict__ topScore,
                                                        const float* __restrict__ topBox,
                                                        const int* __restrict__ topCls,
                                                        const int* __restrict__ keep,
                                                        float* __restrict__ out) {
    __shared__ int sk[TOPK];
    __shared__ int sel[MAXDET];
    int b = blockIdx.x;
    int i = threadIdx.x;
    int kp = keep[b * TOPK + i];
    sk[i] = kp;
    __syncthreads();
    // inclusive Hillis-Steele scan over 1024
    for (int off = 1; off < TOPK; off <<= 1) {
        int add = (i >= off) ? sk[i - off] : 0;
        __syncthreads();
        sk[i] += add;
        __syncthreads();
    }
    int nk = sk[TOPK - 1];
    int incl = sk[i];
    int kexcl = incl - kp;       // exclusive kept rank
    int sexcl = i - kexcl;       // exclusive suppressed rank
    if (kp) {
        if (kexcl < MAXDET) sel[kexcl] = i;
    } else {
        int slot = nk + sexcl;
        if (slot < MAXDET) sel[slot] = i;
    }
    __syncthreads();
    if (i < MAXDET) {
        int p = sel[i];
        float sc = (i < nk) ? topScore[b * TOPK + p] : 0.0f;
        const float* tb = topBox + ((size_t)b * TOPK + p) * 4;
        float* ob = out + ((size_t)b * MAXDET + i) * 4;
        ob[0] = tb[0]; ob[1] = tb[1]; ob[2] = tb[2]; ob[3] = tb[3];
        out[OUT_SCORES + b * MAXDET + i] = sc;
        out[OUT_LABELS + b * MAXDET + i] = (float)topCls[b * TOPK + p];
    }
    if (i == 0) out[OUT_NVALID + b] = (float)(nk < MAXDET ? nk : MAXDET);
}

// ---------------------------------------------------------------------------
extern "C" void kernel_launch(void* const* d_in, const int* in_sizes, int n_in,
                              void* d_out, int out_size, void* d_ws, size_t ws_size,
                              hipStream_t stream) {
    const float* boxes  = (const float*)d_in[0];   // (32, 8400, 4)
    const float* scores = (const float*)d_in[1];   // (32, 8400, 80)
    float* out = (float*)d_out;
    char* ws = (char*)d_ws;

    unsigned long long* segKeys = (unsigned long long*)(ws + WS_SEGKEYS);
    unsigned* segCnt = (unsigned*)(ws + WS_SEGCNT);
    float* topScore = (float*)(ws + WS_TOPSCORE);
    float* topBox = (float*)(ws + WS_TOPBOX);
    int* topCls = (int*)(ws + WS_TOPCLS);
    int* keep = (int*)(ws + WS_KEEP);

    const float4* scores4 = (const float4*)scores;
    const float4* boxes4  = (const float4*)boxes;

    stage_kernel<<<dim3(B_, NSLICE), 256, 0, stream>>>(scores4, segCnt, segKeys);
    sortb_kernel<<<dim3(B_, NBKT), 64, 0, stream>>>(scores4, segKeys, segCnt, boxes4,
                                                    topScore, (float4*)topBox, topCls);
    nms_kernel<<<dim3(B_, C_), 64, 0, stream>>>(topScore, topBox, topCls, keep);
    finalize_kernel<<<B_, 1024, 0, stream>>>(topScore, topBox, topCls, keep, out);
}